// Round 10
// baseline (1007.619 us; speedup 1.0000x reference)
//
#include <hip/hip_runtime.h>
#include <stdint.h>

#define BB 64
#define TT 2048
#define KK 128
#define CH 32         // bi-staging chunk: steps per chunk

typedef float f32x16 __attribute__((ext_vector_type(16)));
typedef float f32x2  __attribute__((ext_vector_type(2)));

__device__ __forceinline__ float waveMax(float v) {
#pragma unroll
    for (int off = 32; off; off >>= 1) v = fmaxf(v, __shfl_xor(v, off, 64));
    return v;
}
__device__ __forceinline__ float waveSum(float v) {
#pragma unroll
    for (int off = 32; off; off >>= 1) v += __shfl_xor(v, off, 64);
    return v;
}
__device__ __forceinline__ int waveSumI(int v) {
#pragma unroll
    for (int off = 32; off; off >>= 1) v += __shfl_xor(v, off, 64);
    return v;
}
// quad reduction via DPP quad_perm (VALU-speed)
__device__ __forceinline__ float quadSum(float s) {
    int x = __builtin_amdgcn_mov_dpp(__float_as_int(s), 0xB1, 0xf, 0xf, true); // xor1
    s += __int_as_float(x);
    x = __builtin_amdgcn_mov_dpp(__float_as_int(s), 0x4E, 0xf, 0xf, true);     // xor2
    s += __int_as_float(x);
    return s;
}
__device__ __forceinline__ float waveMaxFast(float v) {
    int x = __builtin_amdgcn_mov_dpp(__float_as_int(v), 0xB1, 0xf, 0xf, true);
    v = fmaxf(v, __int_as_float(x));
    x = __builtin_amdgcn_mov_dpp(__float_as_int(v), 0x4E, 0xf, 0xf, true);
    v = fmaxf(v, __int_as_float(x));
#pragma unroll
    for (int off = 4; off <= 32; off <<= 1) v = fmaxf(v, __shfl_xor(v, off, 64));
    return v;
}

// ---- DPP primitives (all-VALU, no DS pipe) ----
template<int C> __device__ __forceinline__ float dppMax(float v) {
    int x = __builtin_amdgcn_mov_dpp(__float_as_int(v), C, 0xf, 0xf, true);
    return fmaxf(v, __int_as_float(x));
}
// wave max; result valid in lanes 32..63 (write from lane 63). All-DPP.
__device__ __forceinline__ float waveMaxTo63(float v) {
    v = dppMax<0xB1>(v);
    v = dppMax<0x4E>(v);
    v = dppMax<0x124>(v);
    v = dppMax<0x128>(v);   // each 16-row now holds row-max replicated
    v = dppMax<0x142>(v);   // row_bcast15
    v = dppMax<0x143>(v);   // row_bcast31 -> lanes 32..63 = full max
    return v;
}

// lgkm-only barrier: LDS visibility without draining global prefetch (vmcnt).
__device__ __forceinline__ void lds_barrier() {
    asm volatile("s_waitcnt lgkmcnt(0)\n\ts_barrier" ::: "memory");
}

#define PKFMA(ep, wp, acc) acc = __builtin_elementwise_fma(ep, wp, acc)

#define MATVEC_QUARTER(Wa, Wb, ev, sOut) {                          \
    const float4 e0 = ev[0], e1 = ev[1], e2 = ev[2], e3 = ev[3];    \
    const float4 e4 = ev[4], e5 = ev[5], e6 = ev[6], e7 = ev[7];    \
    f32x2 a0 = {0.f,0.f}, a1 = {0.f,0.f}, a2 = {0.f,0.f}, a3 = {0.f,0.f}; \
    PKFMA(((f32x2){e0.x, e0.y}), ((f32x2){Wa[0],  Wa[1]}),  a0);    \
    PKFMA(((f32x2){e0.z, e0.w}), ((f32x2){Wa[2],  Wa[3]}),  a1);    \
    PKFMA(((f32x2){e1.x, e1.y}), ((f32x2){Wa[4],  Wa[5]}),  a2);    \
    PKFMA(((f32x2){e1.z, e1.w}), ((f32x2){Wa[6],  Wa[7]}),  a3);    \
    PKFMA(((f32x2){e2.x, e2.y}), ((f32x2){Wa[8],  Wa[9]}),  a0);    \
    PKFMA(((f32x2){e2.z, e2.w}), ((f32x2){Wa[10], Wa[11]}), a1);    \
    PKFMA(((f32x2){e3.x, e3.y}), ((f32x2){Wa[12], Wa[13]}), a2);    \
    PKFMA(((f32x2){e3.z, e3.w}), ((f32x2){Wa[14], Wa[15]}), a3);    \
    PKFMA(((f32x2){e4.x, e4.y}), ((f32x2){Wb[0],  Wb[1]}),  a0);    \
    PKFMA(((f32x2){e4.z, e4.w}), ((f32x2){Wb[2],  Wb[3]}),  a1);    \
    PKFMA(((f32x2){e5.x, e5.y}), ((f32x2){Wb[4],  Wb[5]}),  a2);    \
    PKFMA(((f32x2){e5.z, e5.w}), ((f32x2){Wb[6],  Wb[7]}),  a3);    \
    PKFMA(((f32x2){e6.x, e6.y}), ((f32x2){Wb[8],  Wb[9]}),  a0);    \
    PKFMA(((f32x2){e6.z, e6.w}), ((f32x2){Wb[10], Wb[11]}), a1);    \
    PKFMA(((f32x2){e7.x, e7.y}), ((f32x2){Wb[12], Wb[13]}), a2);    \
    PKFMA(((f32x2){e7.z, e7.w}), ((f32x2){Wb[14], Wb[15]}), a3);    \
    const f32x2 s2 = (a0 + a1) + (a2 + a3);                         \
    sOut = s2[0] + s2[1]; }

// ---- W as 64 NAMED f32x2 values pinned into AGPRs (R9, proven resident) ----
#define W_LIST(X) \
    X(0)  X(1)  X(2)  X(3)  X(4)  X(5)  X(6)  X(7)  \
    X(8)  X(9)  X(10) X(11) X(12) X(13) X(14) X(15) \
    X(16) X(17) X(18) X(19) X(20) X(21) X(22) X(23) \
    X(24) X(25) X(26) X(27) X(28) X(29) X(30) X(31) \
    X(32) X(33) X(34) X(35) X(36) X(37) X(38) X(39) \
    X(40) X(41) X(42) X(43) X(44) X(45) X(46) X(47) \
    X(48) X(49) X(50) X(51) X(52) X(53) X(54) X(55) \
    X(56) X(57) X(58) X(59) X(60) X(61) X(62) X(63)

#define WDECL(j) f32x2 W_##j;
#define WINIT_F(j) W_##j = (f32x2){ \
    forb[(2*(j)  )*KK + k] ? 0.0f : __expf(trans[(2*(j)  )*KK + k]), \
    forb[(2*(j)+1)*KK + k] ? 0.0f : __expf(trans[(2*(j)+1)*KK + k]) };
#define WINIT_B(j) W_##j = (f32x2){ \
    forb[k*KK + 2*(j)  ] ? 0.0f : __expf(trans[k*KK + 2*(j)  ]), \
    forb[k*KK + 2*(j)+1] ? 0.0f : __expf(trans[k*KK + 2*(j)+1]) };
#define WPIN(j) asm volatile("" : "+a"(W_##j));   // AGPR-resident, no remat

// ---- readlane matvec term: e pair j via register broadcast (no DS pipe) ----
// lane j of the wave holds ep = (e[2j], e[2j+1]); readlane pulls both scalars
// to SGPRs (uniform), pk_fma consumes (SGPR-pair x AGPR-pair -> VGPR acc).
#define RLFMA(j, A) { \
    const f32x2 E2 = { __int_as_float(__builtin_amdgcn_readlane(epx, (j))), \
                       __int_as_float(__builtin_amdgcn_readlane(epy, (j))) }; \
    PKFMA(E2, W_##j, A); }

// Forward/backward meet-in-the-middle. R9 post-mortem: W fully AGPR-resident
// (VGPR_Count 156) changed NOTHING -> the step is bound by the e-BROADCAST
// return bus (2 waves x 32 uniform ds_read_b128 = 64 KiB/step of replicated
// return traffic, >=512 cyc floor) + barrier/latency stalls. THIS round: the
// broadcast moves off the DS pipe entirely -- one ds_read_b64 per lane grabs
// the whole e vector across the wave, then 128 compile-time readlanes (VALU)
// broadcast the scalars via SGPRs into the pk_fmas. DS per step per wave:
// 1 read + 1 write + 1 bi read.
extern "C" __global__ __launch_bounds__(128, 1)
__attribute__((amdgpu_waves_per_eu(1, 1)))
void crf_fb_kernel(const float* __restrict__ em,
                   const int* __restrict__ mask,
                   const int* __restrict__ tgt,
                   const float* __restrict__ trans,
                   const float* __restrict__ start,
                   const int* __restrict__ forb,
                   float* __restrict__ ef,      // [128][KK] forward exp-alpha
                   float* __restrict__ db,      // [128][KK] backward exp-beta
                   float* __restrict__ Mfb)     // [256] scales: fwd 0..127, bwd 128..255
{
    const int tid  = threadIdx.x;       // 0..127 == output state k
    const int k    = tid;
    const int w    = tid >> 6;
    const int lane = tid & 63;
    const bool fwdDir = (blockIdx.x < 2 * BB);
    const int c    = blockIdx.x & (2 * BB - 1);
    const int b    = c & (BB - 1);
    const bool sup = (c < BB);

    __shared__ __align__(16) float biLDS[2][CH][KK]; // 32 KB composed bi chunks
    __shared__ __align__(16) float eLDS[2][KK];
    __shared__ __align__(8)  float wmLDS[2];
    __shared__ float redLDS[2];
    __shared__ int lenLDS;

    // ---- length ----
    if (tid == 0) lenLDS = 0;
    int ps = 0;
    const int4* __restrict__ mrow = (const int4*)(mask + (size_t)b * TT);
#pragma unroll
    for (int it = 0; it < 4; ++it) {
        const int4 m4 = mrow[tid + 128 * it];
        ps += m4.x + m4.y + m4.z + m4.w;
    }
    ps = waveSumI(ps);
    __syncthreads();                     // lenLDS zeroed before adds
    if (lane == 0) atomicAdd(&lenLDS, ps);

    const float st = start[k];
    const float* __restrict__ emrow = em + (size_t)b * TT * KK;
    const int* __restrict__ trow = tgt + (size_t)b * TT * KK;

    // ---- W in named values, then pin into AGPRs ----
    W_LIST(WDECL)
    if (fwdDir) {
        W_LIST(WINIT_F)
    } else {
        W_LIST(WINIT_B)
    }
    W_LIST(WPIN)                         // opaque + AGPR class: stays resident
    __syncthreads();                     // lenLDS ready
    const int len = lenLDS;              // uniform, in [1024, 2048]
    const int mid = len >> 1;
    const int N   = fwdDir ? mid : (len - 1 - mid);   // serial steps (>=511)
    const int t0  = fwdDir ? 0 : (len - 1);

    // ---- init vector at t0: exact max renorm ----
    float v0 = emrow[(size_t)t0 * KK + k];
    if (sup && !trow[(size_t)t0 * KK + k]) v0 = -100000.0f;
    v0 += st;
    const float wm0 = waveMax(v0);
    if (lane == 0) redLDS[w] = wm0;
    __syncthreads();
    const float M0 = fmaxf(redLDS[0], redLDS[1]);
    double M = (double)M0;
    float eNew = __expf(v0 - M0);
    eLDS[0][k] = eNew;

    // ---- chunked composed-bi staging (R6, proven) ----
    const int scol = (tid & 31) << 2;
    const float4 stc = *(const float4*)(start + scol);
    auto stageChunk = [&](int bf, int m) {
        const int base_n = 1 + CH * m;
        const int t_base = fwdDir ? base_n : (len - base_n - CH);
#pragma unroll
        for (int i = 0; i < 8; ++i) {
            const int row = (tid >> 5) + (i << 2);
            const int t = t_base + row;
            float4 e4 = *(const float4*)(emrow + (size_t)t * KK + scol);
            if (sup) {
                const int4 t4 = *(const int4*)(trow + (size_t)t * KK + scol);
                e4.x = t4.x ? e4.x : -100000.0f;
                e4.y = t4.y ? e4.y : -100000.0f;
                e4.z = t4.z ? e4.z : -100000.0f;
                e4.w = t4.w ? e4.w : -100000.0f;
            }
            e4.x += stc.x; e4.y += stc.y; e4.z += stc.z; e4.w += stc.w;
            *(float4*)&biLDS[bf][row][scol] = e4;
        }
    };

    const int nChunks = (N + CH - 1) / CH;
    int buf = 0;
    stageChunk(0, 0);
    lds_barrier();                       // publish eLDS[0] + biLDS[0]

    for (int m = 0; m < nChunks; ++m) {
        if (m + 1 < nChunks) stageChunk(buf ^ 1, m + 1);
        const int base_n = 1 + CH * m;
        const int rem = N - base_n + 1;
        const int lim = rem < CH ? rem : CH;
#pragma unroll 4
        for (int i = 0; i < lim; ++i) {
            const int n = base_n + i;
            const int p = (n - 1) & 1;

            // whole e vector across the wave: lane j takes pair (e[2j],e[2j+1])
            // (ds_read_b64, 2-way bank aliasing: free). This is the ONLY e read.
            const f32x2 ep = *(const f32x2*)&eLDS[p][lane << 1];
            const int epx = __float_as_int(ep[0]);
            const int epy = __float_as_int(ep[1]);

            // bi from LDS (2-way aliasing: free). bwd final step: bi=0.
            const int pos = fwdDir ? i : (CH - 1 - i);
            float bi = biLDS[buf][pos][k];
            if (!fwdDir && n == N) bi = 0.0f;

            // block-renorm (proven cadence): measure at n%4==3, apply n%4==0.
            if ((n & 3) == 3) {
                const float u = waveMaxTo63(__logf(eNew));
                if (lane == 63) wmLDS[w] = u;
            }
            float r = 0.0f;
            if ((n & 3) == 0) {
                const float2 wmv = *(const float2*)wmLDS;  // uniform b64 bcast
                r = fmaxf(wmv.x, wmv.y);
                M += (double)r;
            }
            const float f = __expf(bi - r);  // overlaps matvec

            // full 128-input dot product: e via readlane SGPR broadcast,
            // W in AGPRs -- zero DS-pipe traffic in the matvec.
            f32x2 a0 = {0.f,0.f}, a1 = {0.f,0.f}, a2 = {0.f,0.f}, a3 = {0.f,0.f};
            RLFMA( 0, a0) RLFMA( 1, a1) RLFMA( 2, a2) RLFMA( 3, a3)
            RLFMA( 4, a0) RLFMA( 5, a1) RLFMA( 6, a2) RLFMA( 7, a3)
            RLFMA( 8, a0) RLFMA( 9, a1) RLFMA(10, a2) RLFMA(11, a3)
            RLFMA(12, a0) RLFMA(13, a1) RLFMA(14, a2) RLFMA(15, a3)
            RLFMA(16, a0) RLFMA(17, a1) RLFMA(18, a2) RLFMA(19, a3)
            RLFMA(20, a0) RLFMA(21, a1) RLFMA(22, a2) RLFMA(23, a3)
            RLFMA(24, a0) RLFMA(25, a1) RLFMA(26, a2) RLFMA(27, a3)
            RLFMA(28, a0) RLFMA(29, a1) RLFMA(30, a2) RLFMA(31, a3)
            RLFMA(32, a0) RLFMA(33, a1) RLFMA(34, a2) RLFMA(35, a3)
            RLFMA(36, a0) RLFMA(37, a1) RLFMA(38, a2) RLFMA(39, a3)
            RLFMA(40, a0) RLFMA(41, a1) RLFMA(42, a2) RLFMA(43, a3)
            RLFMA(44, a0) RLFMA(45, a1) RLFMA(46, a2) RLFMA(47, a3)
            RLFMA(48, a0) RLFMA(49, a1) RLFMA(50, a2) RLFMA(51, a3)
            RLFMA(52, a0) RLFMA(53, a1) RLFMA(54, a2) RLFMA(55, a3)
            RLFMA(56, a0) RLFMA(57, a1) RLFMA(58, a2) RLFMA(59, a3)
            RLFMA(60, a0) RLFMA(61, a1) RLFMA(62, a2) RLFMA(63, a3)
            const f32x2 aa = (a0 + a1) + (a2 + a3);
            const float s = aa[0] + aa[1];

            eNew = s * f;
            eLDS[p ^ 1][k] = eNew;           // 1 ds_write_b32, conflict-free

            lds_barrier();                   // globally-quiet inner barrier
        }
        buf ^= 1;
    }

    (fwdDir ? ef : db)[(size_t)c * KK + k] = eNew;
    if (tid == 0) Mfb[(fwdDir ? 0 : 2 * BB) + c] = (float)M;
}

// z[c] = Mf[c] + Mb[c] + log(dot(ef[c], db[c])); out[b] = z[b] - z[b+64]
extern "C" __global__ void crf_combine_kernel(const float* __restrict__ ef,
                                              const float* __restrict__ db,
                                              const float* __restrict__ Mfb,
                                              float* __restrict__ out)
{
    const int b = blockIdx.x;
    const int tid = threadIdx.x;         // 0..127 = state
    const int wv = tid >> 6, lane = tid & 63;
    __shared__ float red[2][2];
    __shared__ float z[2];
#pragma unroll
    for (int s = 0; s < 2; ++s) {
        const int c = b + s * BB;
        const float v = ef[(size_t)c * KK + tid] * db[(size_t)c * KK + tid];
        const float p = waveSum(v);
        if (lane == 0) red[s][wv] = p;
    }
    __syncthreads();
    if (tid < 2) {
        const int c = b + tid * BB;
        z[tid] = Mfb[c] + Mfb[2 * BB + c] + __logf(red[tid][0] + red[tid][1]);
    }
    __syncthreads();
    if (tid == 0) out[b] = z[0] - z[1];
}

// ---------------- fallback (proven): used only if ws is too small ----------
extern "C" __global__ __launch_bounds__(512)
__attribute__((amdgpu_waves_per_eu(2, 2)))
void crf_chain_kernel(const float* __restrict__ em, const int* __restrict__ mask,
                      const int* __restrict__ tgt, const float* __restrict__ trans,
                      const float* __restrict__ start, const int* __restrict__ forb,
                      float* __restrict__ zbuf)
{
    const int tid = threadIdx.x;
    const int k = tid >> 2, q = tid & 3, w = tid >> 6, lane = tid & 63;
    const int c = blockIdx.x, b = c & (BB - 1);
    const bool sup = (c < BB);
    __shared__ __align__(16) float eLDS[2][KK];
    __shared__ float wmLDS[8];
    __shared__ float redLDS[8];
    __shared__ int lenLDS;
    if (tid == 0) lenLDS = 0;
    const int4 m4 = ((const int4*)(mask + (size_t)b * TT))[tid];
    int ps = m4.x + m4.y + m4.z + m4.w;
    ps = waveSumI(ps);
    __syncthreads();
    if (lane == 0) atomicAdd(&lenLDS, ps);
    const float st = start[k];
    const float* __restrict__ emrow = em + (size_t)b * TT * KK;
    const int* __restrict__ trow = tgt + (size_t)b * TT * KK;
    const int ib = q * 32;
    f32x16 Wa, Wb;
#pragma unroll
    for (int j = 0; j < 16; ++j) {
        Wa[j] = forb[(ib + j     ) * KK + k] ? 0.0f : __expf(trans[(ib + j     ) * KK + k]);
        Wb[j] = forb[(ib + 16 + j) * KK + k] ? 0.0f : __expf(trans[(ib + 16 + j) * KK + k]);
    }
    float v0 = emrow[k];
    if (sup && !trow[k]) v0 = -100000.0f;
    v0 += st;
    const float wm0 = waveMax(v0);
    if (lane == 0) redLDS[w] = wm0;
    __syncthreads();
    const int len = lenLDS;
    float M0 = fmaxf(fmaxf(fmaxf(redLDS[0], redLDS[1]), fmaxf(redLDS[2], redLDS[3])),
                     fmaxf(fmaxf(redLDS[4], redLDS[5]), fmaxf(redLDS[6], redLDS[7])));
    double M = (double)M0;
    float eNew = __expf(v0 - M0);
    if (q == 0) eLDS[0][k] = eNew;
    auto bival = [&](int t) -> float {
        float e0 = emrow[(size_t)t * KK + k];
        if (sup) { if (!trow[(size_t)t * KK + k]) e0 = -100000.0f; }
        return e0 + st;
    };
    float biA = (len > 1) ? bival(1) : 0.0f;
    float biB = (len > 2) ? bival(2) : 0.0f;
    float biC = (len > 3) ? bival(3) : 0.0f;
    float biD = (len > 4) ? bival(4) : 0.0f;
    float sPrev = 1.0f, baPrev = 0.0f;
    lds_barrier();
#pragma unroll 4
    for (int t = 1; t < len; ++t) {
        const int p = (t - 1) & 1;
        const float biN = (t + 4 < len) ? bival(t + 4) : 0.0f;
        if ((t & 3) == 3) {
            const float u = __logf(sPrev) + baPrev;
            const float wmx = waveMaxFast(u);
            if (lane == 0) wmLDS[w] = wmx;
        }
        float r = 0.0f;
        if ((t & 3) == 0) {
            r = fmaxf(fmaxf(fmaxf(wmLDS[0], wmLDS[1]), fmaxf(wmLDS[2], wmLDS[3])),
                      fmaxf(fmaxf(wmLDS[4], wmLDS[5]), fmaxf(wmLDS[6], wmLDS[7])));
            M += (double)r;
        }
        const float ba = biA - r;
        const float f = __expf(ba);
        const float4* __restrict__ ev = (const float4*)eLDS[p] + q * 8;
        float s;
        MATVEC_QUARTER(Wa, Wb, ev, s)
        s = quadSum(s);
        eNew = s * f;
        if (q == 0) eLDS[p ^ 1][k] = eNew;
        sPrev = s; baPrev = ba;
        biA = biB; biB = biC; biC = biD; biD = biN;
        lds_barrier();
    }
    const float sm = waveSum((q == 0) ? eNew : 0.0f);
    if (lane == 0) redLDS[w] = sm;
    __syncthreads();
    if (tid == 0) {
        const float ss = ((redLDS[0] + redLDS[1]) + (redLDS[2] + redLDS[3]))
                       + ((redLDS[4] + redLDS[5]) + (redLDS[6] + redLDS[7]));
        zbuf[c] = (float)(M + (double)__logf(ss));
    }
}

extern "C" __global__ void crf_final_kernel(const float* __restrict__ z,
                                            float* __restrict__ out)
{
    const int b = threadIdx.x;
    out[b] = z[b] - z[b + BB];
}

extern "C" void kernel_launch(void* const* d_in, const int* in_sizes, int n_in,
                              void* d_out, int out_size, void* d_ws, size_t ws_size,
                              hipStream_t stream) {
    const float* em    = (const float*)d_in[0];
    const int*   mask  = (const int*)d_in[1];
    const int*   tgt   = (const int*)d_in[2];
    const float* trans = (const float*)d_in[3];
    const float* start = (const float*)d_in[4];
    const int*   forb  = (const int*)d_in[5];

    const size_t need = (size_t)(2 * 2 * BB * KK + 4 * BB) * sizeof(float); // 132 KB
    if (ws_size >= need) {
        float* ef  = (float*)d_ws;                       // [128][128]
        float* db  = ef + 2 * BB * KK;                   // [128][128]
        float* Mfb = db + 2 * BB * KK;                   // [256]
        crf_fb_kernel<<<4 * BB, 128, 0, stream>>>(em, mask, tgt, trans, start,
                                                  forb, ef, db, Mfb);
        crf_combine_kernel<<<BB, 128, 0, stream>>>(ef, db, Mfb, (float*)d_out);
    } else {
        float* zbuf = (float*)d_ws;
        crf_chain_kernel<<<2 * BB, 512, 0, stream>>>(em, mask, tgt, trans, start,
                                                     forb, zbuf);
        crf_final_kernel<<<1, BB, 0, stream>>>(zbuf, (float*)d_out);
    }
}